// Round 1
// baseline (358.822 us; speedup 1.0000x reference)
//
#include <hip/hip_runtime.h>
#include <hip/hip_cooperative_groups.h>

namespace cg = cooperative_groups;

#define IN_FEATS 128

__device__ __forceinline__ float dot4(float4 a, float4 b) {
    return a.x * b.x + a.y * b.y + a.z * b.z + a.w * b.w;
}

// ---------------------------------------------------------------------------
// Phase A (shared device body): per-node partial scores into a float2 table.
//   s[n].x = dot(h[n], W[0:128]) + bias     (src half, bias folded once)
//   s[n].y = dot(h[n], W[128:256])          (dst half)
// 8 lanes per 512 B row: each lane loads 4 independent float4 (64 B), then a
// 3-level __shfl_xor butterfly (masks <= 4 stay in the 8-lane group).
// 32 rows per 256-thread block per iteration.
// ---------------------------------------------------------------------------
__device__ __forceinline__ void node_phase(const float* __restrict__ h,
                                           const float* __restrict__ W,
                                           float bias,
                                           float2* __restrict__ s,
                                           int n_nodes,
                                           int block_base,
                                           int grid_stride) {
    const int tid = threadIdx.x;
    const int grp = tid >> 3;     // 32 row-groups per block
    const int l8  = tid & 7;

    const float4* Ws4 = (const float4*)W;              // 32 float4 (src half)
    const float4* Wd4 = Ws4 + (IN_FEATS / 4);          // 32 float4 (dst half)
    const float4 ws0 = Ws4[l8],      ws1 = Ws4[l8 + 8],
                 ws2 = Ws4[l8 + 16], ws3 = Ws4[l8 + 24];
    const float4 wd0 = Wd4[l8],      wd1 = Wd4[l8 + 8],
                 wd2 = Wd4[l8 + 16], wd3 = Wd4[l8 + 24];

    for (int node = block_base + grp; node < n_nodes; node += grid_stride) {
        const float4* hp = (const float4*)(h + (size_t)node * IN_FEATS);
        float4 x0 = hp[l8];
        float4 x1 = hp[l8 + 8];
        float4 x2 = hp[l8 + 16];
        float4 x3 = hp[l8 + 24];
        float ps = dot4(x0, ws0) + dot4(x1, ws1) + dot4(x2, ws2) + dot4(x3, ws3);
        float pd = dot4(x0, wd0) + dot4(x1, wd1) + dot4(x2, wd2) + dot4(x3, wd3);
        #pragma unroll
        for (int m = 4; m > 0; m >>= 1) {
            ps += __shfl_xor(ps, m, 64);
            pd += __shfl_xor(pd, m, 64);
        }
        if (l8 == 0) s[node] = make_float2(ps + bias, pd);
    }
}

// ---------------------------------------------------------------------------
// Fused cooperative kernel: phase A -> grid sync -> phase B (edge gather).
// Edge indices for phase B are prefetched BEFORE the node loop so their HBM
// latency hides under phase A. __threadfence() around grid.sync() writes the
// dirty s-lines back past the per-XCD L2s (not cross-coherent) before the
// cross-XCD gathers.
// ---------------------------------------------------------------------------
__global__ void __launch_bounds__(256, 4)
fused_kernel(const float* __restrict__ h,
             const int* __restrict__ src_idx,
             const int* __restrict__ dst_idx,
             const float* __restrict__ W,
             const float* __restrict__ bptr,
             float2* __restrict__ s,
             float* __restrict__ out,
             int n_nodes, int n_edges) {
    const int gsz  = gridDim.x * blockDim.x;
    const int gtid = blockIdx.x * blockDim.x + threadIdx.x;
    const int n_g4 = n_edges >> 2;   // full groups of 4 edges

    // Prefetch this thread's first edge-index group (used only after sync).
    int4 pf_s = make_int4(0, 0, 0, 0), pf_d = make_int4(0, 0, 0, 0);
    if (gtid < n_g4) {
        pf_s = ((const int4*)src_idx)[gtid];
        pf_d = ((const int4*)dst_idx)[gtid];
    }

    node_phase(h, W, bptr[0], s, n_nodes, blockIdx.x * 32, gridDim.x * 32);

    __threadfence();            // release: write s back past per-XCD L2
    cg::this_grid().sync();
    __threadfence();            // acquire

    for (int g = gtid; g < n_g4; g += gsz) {
        int4 a = pf_s, c = pf_d;
        if (g != gtid) {        // only taken if grid can't cover n_g4 in one pass
            a = ((const int4*)src_idx)[g];
            c = ((const int4*)dst_idx)[g];
        }
        float4 o;
        o.x = s[a.x].x + s[c.x].y;
        o.y = s[a.y].x + s[c.y].y;
        o.z = s[a.z].x + s[c.z].y;
        o.w = s[a.w].x + s[c.w].y;
        ((float4*)out)[g] = o;
    }
    for (int e = (n_g4 << 2) + gtid; e < n_edges; e += gsz)
        out[e] = s[src_idx[e]].x + s[dst_idx[e]].y;
}

// ---------------------------------------------------------------------------
// Fallback split path (if cooperative launch is rejected).
// ---------------------------------------------------------------------------
__global__ void __launch_bounds__(256)
node_partial_kernel(const float* __restrict__ h,
                    const float* __restrict__ W,
                    const float* __restrict__ bptr,
                    float2* __restrict__ s,
                    int n_nodes) {
    node_phase(h, W, bptr[0], s, n_nodes, blockIdx.x * 32, gridDim.x * 32);
}

__global__ void __launch_bounds__(256)
edge_score_kernel(const int* __restrict__ src_idx,
                  const int* __restrict__ dst_idx,
                  const float2* __restrict__ s,
                  float* __restrict__ out,
                  int n_edges) {
    const int gsz  = gridDim.x * blockDim.x;
    const int gtid = blockIdx.x * blockDim.x + threadIdx.x;
    const int n_g4 = n_edges >> 2;
    for (int g = gtid; g < n_g4; g += gsz) {
        int4 a = ((const int4*)src_idx)[g];
        int4 c = ((const int4*)dst_idx)[g];
        float4 o;
        o.x = s[a.x].x + s[c.x].y;
        o.y = s[a.y].x + s[c.y].y;
        o.z = s[a.z].x + s[c.z].y;
        o.w = s[a.w].x + s[c.w].y;
        ((float4*)out)[g] = o;
    }
    for (int e = (n_g4 << 2) + gtid; e < n_edges; e += gsz)
        out[e] = s[src_idx[e]].x + s[dst_idx[e]].y;
}

// ---------------------------------------------------------------------------
// Fallback (workspace too small): direct per-edge dot product.
// ---------------------------------------------------------------------------
__global__ void __launch_bounds__(256)
edge_direct_kernel(const float* __restrict__ h,
                   const int* __restrict__ src_idx,
                   const int* __restrict__ dst_idx,
                   const float* __restrict__ W,
                   const float* __restrict__ bptr,
                   float* __restrict__ out,
                   int n_edges) {
    int e = blockIdx.x * blockDim.x + threadIdx.x;
    if (e >= n_edges) return;
    const float4* hs = (const float4*)(h + (size_t)src_idx[e] * IN_FEATS);
    const float4* hd = (const float4*)(h + (size_t)dst_idx[e] * IN_FEATS);
    const float4* Ws = (const float4*)W;
    const float4* Wd = (const float4*)(W + IN_FEATS);
    float acc = bptr[0];
    #pragma unroll
    for (int k = 0; k < IN_FEATS / 4; ++k) {
        float4 a = hs[k], w = Ws[k];
        acc += a.x * w.x + a.y * w.y + a.z * w.z + a.w * w.w;
        float4 c = hd[k], u = Wd[k];
        acc += c.x * u.x + c.y * u.y + c.z * u.z + c.w * u.w;
    }
    out[e] = acc;
}

extern "C" void kernel_launch(void* const* d_in, const int* in_sizes, int n_in,
                              void* d_out, int out_size, void* d_ws, size_t ws_size,
                              hipStream_t stream) {
    const float* h       = (const float*)d_in[0];
    const int*   src_idx = (const int*)d_in[1];
    const int*   dst_idx = (const int*)d_in[2];
    const float* W       = (const float*)d_in[3];
    const float* b       = (const float*)d_in[4];
    float*       out     = (float*)d_out;

    const int n_nodes = in_sizes[0] / IN_FEATS;
    const int n_edges = in_sizes[1];

    const size_t ws_needed = (size_t)n_nodes * sizeof(float2);

    if (ws_size >= ws_needed) {
        float2* s = (float2*)d_ws;

        // 1024 blocks x 256 threads; __launch_bounds__(256,4) -> >=4 blocks/CU
        // on 256 CUs, so 1024 blocks are guaranteed co-resident.
        void* args[] = { (void*)&h, (void*)&src_idx, (void*)&dst_idx,
                         (void*)&W, (void*)&b, (void*)&s, (void*)&out,
                         (void*)&n_nodes, (void*)&n_edges };
        hipError_t err = hipLaunchCooperativeKernel(
            reinterpret_cast<void*>(fused_kernel),
            dim3(1024), dim3(256), args, 0, stream);

        if (err != hipSuccess) {
            // Split path: two ordinary launches (stream order gives the
            // dependency + L2 writeback at the kernel boundary).
            int g1 = (n_nodes + 31) / 32;
            node_partial_kernel<<<g1, 256, 0, stream>>>(h, W, b, s, n_nodes);
            int n_g4 = n_edges >> 2;
            int g2 = (n_g4 + 255) / 256;
            if (g2 < 1) g2 = 1;
            edge_score_kernel<<<g2, 256, 0, stream>>>(src_idx, dst_idx, s, out,
                                                      n_edges);
        }
    } else {
        int grid = (n_edges + 255) / 256;
        edge_direct_kernel<<<grid, 256, 0, stream>>>(h, src_idx, dst_idx, W, b,
                                                     out, n_edges);
    }
}

// Round 2
// 102.753 us; speedup vs baseline: 3.4921x; 3.4921x over previous
//
#include <hip/hip_runtime.h>

#define IN_FEATS 128

__device__ __forceinline__ float dot4(float4 a, float4 b) {
    return a.x * b.x + a.y * b.y + a.z * b.z + a.w * b.w;
}

// ---------------------------------------------------------------------------
// Phase 1: per-node partial scores into a packed float2 table.
//   s[n].x = dot(h[n], W[0:128]) + bias     (src half, bias folded once)
//   s[n].y = dot(h[n], W[128:256])          (dst half)
// 8 lanes per 512 B row: each lane loads 4 independent float4 (64 B of the
// row), then a 3-level __shfl_xor butterfly (masks <= 4 stay within the
// 8-lane group). 32 rows per 256-thread block; grid covers nodes exactly.
// ---------------------------------------------------------------------------
__global__ void __launch_bounds__(256)
node_partial_kernel(const float* __restrict__ h,
                    const float* __restrict__ W,
                    const float* __restrict__ bptr,
                    float2* __restrict__ s,
                    int n_nodes) {
    const int tid  = threadIdx.x;
    const int grp  = tid >> 3;      // 32 row-groups per block
    const int l8   = tid & 7;
    const int node = blockIdx.x * 32 + grp;
    if (node >= n_nodes) return;    // uniform per 8-lane group

    const float4* hp = (const float4*)(h + (size_t)node * IN_FEATS);
    float4 x0 = hp[l8];
    float4 x1 = hp[l8 + 8];
    float4 x2 = hp[l8 + 16];
    float4 x3 = hp[l8 + 24];

    const float4* Ws4 = (const float4*)W;            // 32 float4 (src half)
    const float4* Wd4 = Ws4 + (IN_FEATS / 4);        // 32 float4 (dst half)
    float4 ws0 = Ws4[l8],      ws1 = Ws4[l8 + 8],
           ws2 = Ws4[l8 + 16], ws3 = Ws4[l8 + 24];
    float4 wd0 = Wd4[l8],      wd1 = Wd4[l8 + 8],
           wd2 = Wd4[l8 + 16], wd3 = Wd4[l8 + 24];

    float ps = dot4(x0, ws0) + dot4(x1, ws1) + dot4(x2, ws2) + dot4(x3, ws3);
    float pd = dot4(x0, wd0) + dot4(x1, wd1) + dot4(x2, wd2) + dot4(x3, wd3);

    #pragma unroll
    for (int m = 4; m > 0; m >>= 1) {
        ps += __shfl_xor(ps, m, 64);
        pd += __shfl_xor(pd, m, 64);
    }
    if (l8 == 0) s[node] = make_float2(ps + bptr[0], pd);
}

// ---------------------------------------------------------------------------
// Phase 2: per-edge gather of the two scalars. 4 edges per thread via int4
// index loads; the 800 KB score table is L2/L3-resident after phase 1.
// ---------------------------------------------------------------------------
__global__ void __launch_bounds__(256)
edge_score_kernel(const int* __restrict__ src_idx,
                  const int* __restrict__ dst_idx,
                  const float2* __restrict__ s,
                  float* __restrict__ out,
                  int n_edges) {
    const int g    = blockIdx.x * blockDim.x + threadIdx.x;
    const int n_g4 = n_edges >> 2;

    if (g < n_g4) {
        int4 a = ((const int4*)src_idx)[g];
        int4 c = ((const int4*)dst_idx)[g];
        float4 o;
        o.x = s[a.x].x + s[c.x].y;
        o.y = s[a.y].x + s[c.y].y;
        o.z = s[a.z].x + s[c.z].y;
        o.w = s[a.w].x + s[c.w].y;
        ((float4*)out)[g] = o;
    }
    // Ragged tail (none for n_edges % 4 == 0).
    const int tail = n_g4 << 2;
    for (int e = tail + g; e < n_edges; e += gridDim.x * blockDim.x)
        out[e] = s[src_idx[e]].x + s[dst_idx[e]].y;
}

// ---------------------------------------------------------------------------
// Fallback (workspace too small): direct per-edge dot product.
// ---------------------------------------------------------------------------
__global__ void __launch_bounds__(256)
edge_direct_kernel(const float* __restrict__ h,
                   const int* __restrict__ src_idx,
                   const int* __restrict__ dst_idx,
                   const float* __restrict__ W,
                   const float* __restrict__ bptr,
                   float* __restrict__ out,
                   int n_edges) {
    int e = blockIdx.x * blockDim.x + threadIdx.x;
    if (e >= n_edges) return;
    const float4* hs = (const float4*)(h + (size_t)src_idx[e] * IN_FEATS);
    const float4* hd = (const float4*)(h + (size_t)dst_idx[e] * IN_FEATS);
    const float4* Ws = (const float4*)W;
    const float4* Wd = (const float4*)(W + IN_FEATS);
    float acc = bptr[0];
    #pragma unroll
    for (int k = 0; k < IN_FEATS / 4; ++k) {
        float4 a = hs[k], w = Ws[k];
        acc += a.x * w.x + a.y * w.y + a.z * w.z + a.w * w.w;
        float4 c = hd[k], u = Wd[k];
        acc += c.x * u.x + c.y * u.y + c.z * u.z + c.w * u.w;
    }
    out[e] = acc;
}

extern "C" void kernel_launch(void* const* d_in, const int* in_sizes, int n_in,
                              void* d_out, int out_size, void* d_ws, size_t ws_size,
                              hipStream_t stream) {
    const float* h       = (const float*)d_in[0];
    const int*   src_idx = (const int*)d_in[1];
    const int*   dst_idx = (const int*)d_in[2];
    const float* W       = (const float*)d_in[3];
    const float* b       = (const float*)d_in[4];
    float*       out     = (float*)d_out;

    const int n_nodes = in_sizes[0] / IN_FEATS;
    const int n_edges = in_sizes[1];

    const size_t ws_needed = (size_t)n_nodes * sizeof(float2);

    if (ws_size >= ws_needed) {
        float2* s = (float2*)d_ws;

        // Phase 1: 32 nodes per 256-thread block (8 lanes per 128-f row).
        int grid1 = (n_nodes + 31) / 32;
        node_partial_kernel<<<grid1, 256, 0, stream>>>(h, W, b, s, n_nodes);

        // Phase 2: 4 edges per thread.
        int n_g4  = n_edges >> 2;
        int grid2 = (n_g4 + 255) / 256;
        if (grid2 < 1) grid2 = 1;
        edge_score_kernel<<<grid2, 256, 0, stream>>>(src_idx, dst_idx, s, out,
                                                     n_edges);
    } else {
        int grid = (n_edges + 255) / 256;
        edge_direct_kernel<<<grid, 256, 0, stream>>>(h, src_idx, dst_idx, W, b,
                                                     out, n_edges);
    }
}